// Round 8
// baseline (504.024 us; speedup 1.0000x reference)
//
#include <hip/hip_runtime.h>
#include <math.h>

#define B_   8
#define Hs   56
#define Ws   56
#define Cc   768
#define NHh  12
#define HDd  64
#define Nt   3137
#define HW_  3136
#define C3   2304
#define SCALE 0.125f
#define Mrows (B_ * Nt)        // 25096
#define Mpad  (99 * 256)       // 25344 (multiple of 256 and 128)

typedef _Float16 half8  __attribute__((ext_vector_type(8)));
typedef _Float16 half4  __attribute__((ext_vector_type(4)));
typedef _Float16 half2_ __attribute__((ext_vector_type(2)));
typedef float floatx4 __attribute__((ext_vector_type(4)));

#define WAITV(N) asm volatile("s_waitcnt vmcnt(" #N ")" ::: "memory")
#define WAITL    asm volatile("s_waitcnt lgkmcnt(0)" ::: "memory")

__device__ __forceinline__ void barrier_mem() {
    asm volatile("" ::: "memory");
    __builtin_amdgcn_s_barrier();
    asm volatile("" ::: "memory");
}

__device__ __forceinline__ void gload_lds16(const _Float16* g, _Float16* l) {
    __builtin_amdgcn_global_load_lds(
        (const __attribute__((address_space(1))) void*)g,
        (__attribute__((address_space(3))) void*)l, 16, 0, 0);
}

// ---------------- scratch (__device__ globals) -----------------------------
__device__ _Float16 g_qkvh[(size_t)Mrows * C3];          // fp16 qkv (115 MB)
__device__ float    g_Ocol[(size_t)B_ * NHh * HW_ * HDd];
__device__ float    g_mcol[(size_t)B_ * NHh * HW_];
__device__ float    g_lcol[(size_t)B_ * NHh * HW_];
__device__ _Float16 g_xh[(size_t)Mpad * Cc];
__device__ _Float16 g_attH[(size_t)Mpad * Cc];
__device__ _Float16 g_WqkvT[(size_t)C3 * Cc];
__device__ _Float16 g_WprojT[(size_t)Cc * Cc];
__device__ float    g_clsP[(size_t)B_ * NHh * 4 * 66];   // per-partial: m,l,O[64]

// ---------------- fp32 -> fp16 convert -------------------------------------
__global__ __launch_bounds__(256) void cvt_f16(
    const float* __restrict__ in, _Float16* __restrict__ out, int n4)
{
    for (int i = blockIdx.x * 256 + threadIdx.x; i < n4; i += gridDim.x * 256) {
        float4 v = ((const float4*)in)[i];
        half4 h = { (_Float16)v.x, (_Float16)v.y, (_Float16)v.z, (_Float16)v.w };
        ((half4*)out)[i] = h;
    }
}

// ---------------- fp32 [R][Cq] -> fp16 transposed [Cq][R] ------------------
__global__ __launch_bounds__(256) void transpose_f16(
    const float* __restrict__ in, _Float16* __restrict__ out, int R, int Cq)
{
    __shared__ float t[32][33];
    const int c0 = blockIdx.x * 32, r0 = blockIdx.y * 32;
    const int tx = threadIdx.x & 31, ty = threadIdx.x >> 5;
#pragma unroll
    for (int i = 0; i < 32; i += 8)
        t[ty + i][tx] = in[(size_t)(r0 + ty + i) * Cq + c0 + tx];
    __syncthreads();
#pragma unroll
    for (int i = 0; i < 32; i += 8)
        out[(size_t)(c0 + ty + i) * R + r0 + tx] = (_Float16)t[tx][ty + i];
}

// ---------------------------------------------------------------------------
// fp16 MFMA GEMM: C[M,Nd] = A[Mpad,K] @ Bt[Nd,K]^T (+bias).
// R8: m201-style phase discipline on R7's buffers. BMx256 tile, BK=32,
// 512 thr (8 waves 2Mx4N). FOUR rotating LDS buffers, staging depth-3,
// counted vmcnt GATE once per tile (outstanding = 2 younger tiles, never 0
// until the tail peel). Per tile, TWO phases (BM=256) each shaped as m201:
//   { ds_read subtile (pre-barrier)  ||  stage half of tile t+3 }
//   barrier;  lgkmcnt(0); sched_barrier(0);           // rule #18 fence
//   setprio(1); 16 MFMA; setprio(0); barrier;
// Reads drain during the barrier arrival skew; setprio arbitrates the two
// waves per SIMD whose phases now interleave (T3+T4+T5 per catalog).
// Race-freedom: reads of buf(t) lie between gate(t) and tile t's closing
// barrier; stage(t+3) targets buf(t-1), drained >= 2 barriers earlier.
// MFMA order per accumulator identical to R7 -> bit-identical numerics.
// ---------------------------------------------------------------------------
template <typename OutT, int BM>
__global__ __launch_bounds__(512, 2) void gemm_f16(
    const _Float16* __restrict__ A, const _Float16* __restrict__ Bt,
    const float* __restrict__ bias, OutT* __restrict__ Cm,
    int M, int Nd, int K)
{
    constexpr int MI   = BM / 32;        // 16-row groups per wave (8 or 4)
    constexpr int LA   = BM / 128;       // A loads/thread per K-tile (2 or 1)
    constexpr int ASZh = BM * 32;        // halfs per A K-tile buffer
    constexpr int BSZh = 256 * 32;       // halfs per B K-tile buffer
    constexpr int BUFh = ASZh + BSZh;
    constexpr size_t MAINB = (size_t)4 * BUFh * 2;
    constexpr size_t EPIB  = sizeof(OutT) == 2 ? (size_t)BM * 280 * 2
                                               : (size_t)BM * 140 * 4;
    constexpr size_t SMEMB = MAINB > EPIB ? MAINB : EPIB;
    __shared__ __align__(16) char smem[SMEMB];

    const int tid = threadIdx.x;
    const int wave = tid >> 6, lane = tid & 63;
    const int wm = wave & 1, wn = wave >> 1;

    // panel swizzle: 16 row-blocks per panel, col-major within panel
    const int bid = blockIdx.y * gridDim.x + blockIdx.x;
    const int perPanel = gridDim.x * 16;
    const int panel = bid / perPanel;
    const int rowsIn = min(16, (int)gridDim.y - panel * 16);
    const int rem = bid - panel * perPanel;
    const int by = panel * 16 + rem % rowsIn;
    const int bx = rem / rowsIn;
    const int mBase = by * BM, nBase = bx * 256;

    // staging geometry (verified): unit u (16B) -> row ((u>>6)<<4)+(u&15),
    // kc=(u>>4)&3, LDS byte off u*16. Thread handles u = i*512 + tid.
    const int mU  = ((tid >> 6) << 4) + (tid & 15);
    const int kcU = (tid >> 4) & 3;
    const _Float16* ga = A  + (size_t)(mBase + mU) * K + kcU * 8;
    const _Float16* gb = Bt + (size_t)(nBase + mU) * K + kcU * 8;

    auto stageA = [&](int t) {
        char* base = smem + (size_t)(t & 3) * (BUFh * 2);
        _Float16* lA = (_Float16*)base + wave * 512;
        const _Float16* gaK = ga + t * 32;
#pragma unroll
        for (int i = 0; i < LA; ++i)
            gload_lds16(gaK + (size_t)i * 128 * K, lA + i * 4096);
    };
    auto stageB = [&](int t) {
        char* base = smem + (size_t)(t & 3) * (BUFh * 2);
        _Float16* lB = (_Float16*)base + ASZh + wave * 512;
        const _Float16* gbK = gb + t * 32;
#pragma unroll
        for (int i = 0; i < 2; ++i)
            gload_lds16(gbK + (size_t)i * 128 * K, lB + i * 4096);
    };

    // fragment read: group g (16 rows x 32 k = 512 halfs); conflict-free b128
    const int fo = (lane >> 4) * 128 + (lane & 15) * 8;

    floatx4 acc[MI][4] = {};

    const int NT = K >> 5;               // 24 K-tiles of 32
    stageA(0); stageB(0); stageA(1); stageB(1); stageA(2); stageB(2);

    for (int t = 0; t < NT; ++t) {
        const _Float16* bufA = (const _Float16*)(smem + (size_t)(t & 3) * (BUFh * 2));
        const _Float16* bufB = bufA + ASZh;
        const bool st = (t + 3 < NT);

        // ---- gate: tile t resident; 2 younger tiles stay in flight ----
        if (t <= NT - 3)      { if constexpr (LA == 2) { WAITV(8); } else { WAITV(6); } }
        else if (t == NT - 2) { if constexpr (LA == 2) { WAITV(4); } else { WAITV(3); } }
        else                  { WAITV(0); }
        barrier_mem();

        // ---- phase 0: reads (pre-barrier) || stage A(t+3) ----
        half8 b0[4], a0[4];
#pragma unroll
        for (int ni = 0; ni < 4; ++ni)
            b0[ni] = *(const half8*)&bufB[(wn * 4 + ni) * 512 + fo];
#pragma unroll
        for (int mi = 0; mi < 4 && mi < MI; ++mi)
            a0[mi] = *(const half8*)&bufA[(wm * MI + mi) * 512 + fo];
        if (st) stageA(t + 3);
        if constexpr (MI == 4) { if (st) stageB(t + 3); }
        barrier_mem();
        WAITL;
        __builtin_amdgcn_sched_barrier(0);
        __builtin_amdgcn_s_setprio(1);
#pragma unroll
        for (int mi = 0; mi < 4 && mi < MI; ++mi)
#pragma unroll
            for (int ni = 0; ni < 4; ++ni)
                acc[mi][ni] = __builtin_amdgcn_mfma_f32_16x16x32_f16(
                    b0[ni], a0[mi], acc[mi][ni], 0, 0, 0);
        __builtin_amdgcn_s_setprio(0);
        barrier_mem();

        if constexpr (MI == 8) {
            // ---- phase 1: reads a-hi || stage B(t+3) ----
            half8 a1[4];
#pragma unroll
            for (int mi = 0; mi < 4; ++mi)
                a1[mi] = *(const half8*)&bufA[(wm * MI + 4 + mi) * 512 + fo];
            if (st) stageB(t + 3);
            barrier_mem();
            WAITL;
            __builtin_amdgcn_sched_barrier(0);
            __builtin_amdgcn_s_setprio(1);
#pragma unroll
            for (int mi = 0; mi < 4; ++mi)
#pragma unroll
                for (int ni = 0; ni < 4; ++ni)
                    acc[4 + mi][ni] = __builtin_amdgcn_mfma_f32_16x16x32_f16(
                        b0[ni], a1[mi], acc[4 + mi][ni], 0, 0, 0);
            __builtin_amdgcn_s_setprio(0);
            barrier_mem();
        }
    }
    WAITL;
    barrier_mem();                        // LDS free for epilogue reuse

    // -------- epilogue: LDS bounce --------
    const int mlBase = wm * (BM / 2) + (lane & 15);
    const int nlBase = wn * 64 + ((lane >> 4) << 2);

    if constexpr (sizeof(OutT) == 2) {
        _Float16* Ch = (_Float16*)smem;          // [BM][280]
#pragma unroll
        for (int ni = 0; ni < 4; ++ni) {
            const int nl = nlBase + ni * 16;
#pragma unroll
            for (int mi = 0; mi < MI; ++mi) {
                const int ml = mlBase + mi * 16;
                floatx4 v = acc[mi][ni];
                half4 h = { (_Float16)v[0], (_Float16)v[1],
                            (_Float16)v[2], (_Float16)v[3] };
                *(half4*)&Ch[ml * 280 + nl] = h;
            }
        }
        barrier_mem();
#pragma unroll
        for (int i = 0; i < BM / 16; ++i) {
            const int f = i * 512 + tid;
            const int row = f >> 5, u = f & 31;
            const int gm = mBase + row;
            if (gm < M)
                *(half8*)&Cm[(size_t)gm * Nd + nBase + u * 8] =
                    *(const half8*)&Ch[row * 280 + u * 8];
        }
    } else {
        float* Cf = (float*)smem;                // [BM][140]
#pragma unroll
        for (int nh = 0; nh < 2; ++nh) {
            barrier_mem();
            if ((wn >> 1) == nh) {
#pragma unroll
                for (int ni = 0; ni < 4; ++ni) {
                    const int n0 = nBase + wn * 64 + ((lane >> 4) << 2) + ni * 16;
                    float4 bv = bias ? *(const float4*)&bias[n0]
                                     : make_float4(0.f, 0.f, 0.f, 0.f);
                    const int nl = (wn & 1) * 64 + ((lane >> 4) << 2) + ni * 16;
#pragma unroll
                    for (int mi = 0; mi < MI; ++mi) {
                        const int ml = mlBase + mi * 16;
                        floatx4 v = acc[mi][ni];
                        float4 o = make_float4(v[0] + bv.x, v[1] + bv.y,
                                               v[2] + bv.z, v[3] + bv.w);
                        *(float4*)&Cf[ml * 140 + nl] = o;
                    }
                }
            }
            barrier_mem();
#pragma unroll
            for (int i = 0; i < BM / 16; ++i) {
                const int f = i * 512 + tid;
                const int row = f >> 5, u = f & 31;
                const int gm = mBase + row;
                if (gm < M)
                    *(float4*)&Cm[(size_t)gm * Nd + nBase + nh * 128 + u * 4] =
                        *(const float4*)&Cf[row * 140 + u * 4];
            }
        }
    }
}

// ---------------------------------------------------------------------------
// R6 MFMA criss-cross attention (unchanged). One wave per (x, nh, b).
// ---------------------------------------------------------------------------
template <int MODE>
__global__ __launch_bounds__(64) void cc_attn(
    const _Float16* __restrict__ qkvh,
    float* __restrict__ Ocol, float* __restrict__ mcol,
    float* __restrict__ lcol, _Float16* __restrict__ attH)
{
    constexpr int NK = (MODE == 0) ? 57 : 56;
    const int x = blockIdx.x, nh = blockIdx.y, b = blockIdx.z;
    const int lane = threadIdx.x;
    const int q15 = lane & 15, g = lane >> 4;

    __shared__ __align__(16) char smem[18944];
    _Float16* Vt = (_Float16*)smem;                 // [64][72], rotated rows
    _Float16* Pl = (_Float16*)(smem + 9216);        // [64][72]
    float*    ML = (float*)(smem + 18432);          // [64] m, [64] l
    float*    Ol = (float*)smem;                    // [64][68] overlay

    const _Float16* base_b = qkvh + (size_t)(b * Nt) * C3 + nh * HDd;

    auto nrow_k = [&](int key) -> int {
        key = min(key, NK - 1);
        if (MODE == 0) return (key == 0) ? 0 : ((key - 1) * Ws + x + 1);
        return x * Ws + key + 1;
    };
    auto nrow_q = [&](int q) -> int {
        q = min(q, 55);
        return (MODE == 0) ? (q * Ws + x + 1) : (x * Ws + q + 1);
    };

    // ---- K/Q fragments from global (per-lane rows) ----
    half8 Kf[4][2], Qf[4][2];
#pragma unroll
    for (int t = 0; t < 4; ++t) {
        const _Float16* kp = base_b + (size_t)nrow_k(t * 16 + q15) * C3 + Cc;
        const _Float16* qp = base_b + (size_t)nrow_q(t * 16 + q15) * C3;
#pragma unroll
        for (int kk = 0; kk < 2; ++kk) {
            Kf[t][kk] = *(const half8*)(kp + kk * 32 + g * 8);
            Qf[t][kk] = *(const half8*)(qp + kk * 32 + g * 8);
        }
    }

    // ---- stage V^T into LDS (rotated, zero-padded keys >= NK) ----
#pragma unroll
    for (int it = 0; it < 8; ++it) {
        const int i = it * 64 + lane;
        const int j = i >> 3, c = i & 7;
        half8 v = {};
        if (j < NK)
            v = *(const half8*)(base_b + (size_t)nrow_k(j) * C3 + 2 * Cc + c * 8);
#pragma unroll
        for (int e = 0; e < 8; ++e)
            Vt[(c * 8 + e) * 72 + ((j + 8 * c) & 63)] = v[e];
    }

    // ---- S^T = K * Q^T ----
    floatx4 S[4][4] = {};   // [kt][qt]
#pragma unroll
    for (int kt = 0; kt < 4; ++kt)
#pragma unroll
        for (int qt = 0; qt < 4; ++qt)
#pragma unroll
            for (int kk = 0; kk < 2; ++kk)
                S[kt][qt] = __builtin_amdgcn_mfma_f32_16x16x32_f16(
                    Kf[kt][kk], Qf[qt][kk], S[kt][qt], 0, 0, 0);

    // ---- softmax per query column (in-lane 16 + cross-g shfl) ----
    float mq[4], lq[4];
#pragma unroll
    for (int qt = 0; qt < 4; ++qt) {
        const int q = qt * 16 + q15;
        float sv[4][4];
        float mm = -1e30f;
#pragma unroll
        for (int kt = 0; kt < 4; ++kt)
#pragma unroll
            for (int r = 0; r < 4; ++r) {
                const int key = kt * 16 + g * 4 + r;
                float s = S[kt][qt][r] * SCALE;
                const bool bad = (key >= NK) || (MODE == 1 && key == q);
                sv[kt][r] = bad ? -1e30f : s;
                mm = fmaxf(mm, sv[kt][r]);
            }
        mm = fmaxf(mm, __shfl_xor(mm, 16, 64));
        mm = fmaxf(mm, __shfl_xor(mm, 32, 64));
        float ll = 0.f;
#pragma unroll
        for (int kt = 0; kt < 4; ++kt) {
            half4 ph;
#pragma unroll
            for (int r = 0; r < 4; ++r) {
                const float p = __expf(sv[kt][r] - mm);
                ll += p;
                ph[r] = (_Float16)p;
            }
            *(half4*)&Pl[q * 72 + kt * 16 + g * 4] = ph;
        }
        ll += __shfl_xor(ll, 16, 64);
        ll += __shfl_xor(ll, 32, 64);
        mq[qt] = mm; lq[qt] = ll;
    }

    if (g == 0) {
        if (MODE == 0) {
#pragma unroll
            for (int qt = 0; qt < 4; ++qt) {
                const int q = qt * 16 + q15;
                if (q < 56) {
                    const size_t qi = (size_t)((b * NHh + nh) * HW_) + q * Ws + x;
                    mcol[qi] = mq[qt]; lcol[qi] = lq[qt];
                }
            }
        } else {
#pragma unroll
            for (int qt = 0; qt < 4; ++qt) {
                ML[qt * 16 + q15] = mq[qt];
                ML[64 + qt * 16 + q15] = lq[qt];
            }
        }
    }
    __syncthreads();

    // ---- O^T = V^T * P^T ----
    half8 Pf[4][2];
#pragma unroll
    for (int qt = 0; qt < 4; ++qt)
#pragma unroll
        for (int kk = 0; kk < 2; ++kk)
            Pf[qt][kk] = *(const half8*)&Pl[(qt * 16 + q15) * 72 + kk * 32 + g * 8];

    floatx4 O[4][4] = {};   // [dt][qt]
#pragma unroll
    for (int dt = 0; dt < 4; ++dt) {
        const int d = dt * 16 + q15;
        const int rot = 8 * (d >> 3);
        half8 Vf0 = *(const half8*)&Vt[d * 72 + ((0 + g * 8 + rot) & 63)];
        half8 Vf1 = *(const half8*)&Vt[d * 72 + ((32 + g * 8 + rot) & 63)];
#pragma unroll
        for (int qt = 0; qt < 4; ++qt) {
            O[dt][qt] = __builtin_amdgcn_mfma_f32_16x16x32_f16(
                Vf0, Pf[qt][0], O[dt][qt], 0, 0, 0);
            O[dt][qt] = __builtin_amdgcn_mfma_f32_16x16x32_f16(
                Vf1, Pf[qt][1], O[dt][qt], 0, 0, 0);
        }
    }
    __syncthreads();   // all Vt/Pl reads done before Ol overlay writes

    // ---- bounce O^T -> row-major rows in LDS ----
#pragma unroll
    for (int dt = 0; dt < 4; ++dt)
#pragma unroll
        for (int qt = 0; qt < 4; ++qt) {
            float4 f = { O[dt][qt][0], O[dt][qt][1], O[dt][qt][2], O[dt][qt][3] };
            *(float4*)&Ol[(qt * 16 + q15) * 68 + dt * 16 + g * 4] = f;
        }
    __syncthreads();

    // ---- per-lane row output ----
    const int qq = lane;
    if (qq < 56) {
        if (MODE == 0) {
            const size_t qi = (size_t)((b * NHh + nh) * HW_) + qq * Ws + x;
            float* op = Ocol + qi * HDd;
#pragma unroll
            for (int i = 0; i < 16; ++i)
                *(float4*)(op + i * 4) = *(const float4*)&Ol[qq * 68 + i * 4];
        } else {
            const size_t qi = (size_t)((b * NHh + nh) * HW_) + x * Ws + qq;
            const float mc = mcol[qi], lc = lcol[qi];
            const float mr = ML[qq], lr = ML[64 + qq];
            const float mn = fmaxf(mc, mr);
            const float fc = __expf(mc - mn);
            const float fr = __expf(mr - mn);
            const float inv = 1.f / (lc * fc + lr * fr);
            const int n = x * Ws + qq + 1;
            _Float16* op = attH + (size_t)(b * Nt + n) * Cc + nh * HDd;
            const float* ocp = Ocol + qi * HDd;
#pragma unroll
            for (int i = 0; i < 16; ++i) {
                float4 oc = *(const float4*)(ocp + i * 4);
                const float* oo = &Ol[qq * 68 + i * 4];
                half4 r = { (_Float16)((oc.x * fc + oo[0] * fr) * inv),
                            (_Float16)((oc.y * fc + oo[1] * fr) * inv),
                            (_Float16)((oc.z * fc + oo[2] * fr) * inv),
                            (_Float16)((oc.w * fc + oo[3] * fr) * inv) };
                *(half4*)(op + i * 4) = r;
            }
        }
    }
}

// ---------------------------------------------------------------------------
// Cls-token attention, 4-way key-split; merged by cls_merge.
// ---------------------------------------------------------------------------
__global__ __launch_bounds__(1024) void cls_part(
    const _Float16* __restrict__ qkvh, float* __restrict__ P)
{
    const int nh = blockIdx.x, b = blockIdx.y, sidx = blockIdx.z;
    const int j0 = sidx * 785, j1 = min(Nt, j0 + 785);
    const int tid = threadIdx.x;
    const int lane = tid & 63, wv = tid >> 6;

    const float qd = (float)qkvh[(size_t)(b * Nt) * C3 + nh * HDd + lane];
    float m = -INFINITY, l = 0.f, Od = 0.f;

    for (int j = j0 + wv; j < j1; j += 16) {
        const _Float16* base = qkvh + (size_t)(b * Nt + j) * C3 + nh * HDd;
        float prod = qd * (float)base[Cc + lane];
#pragma unroll
        for (int off = 32; off >= 1; off >>= 1)
            prod += __shfl_xor(prod, off, 64);
        float s = prod * SCALE;
        float mn = fmaxf(m, s);
        float corr = __expf(m - mn);
        float p = __expf(s - mn);
        l = l * corr + p;
        Od = fmaf(Od, corr, p * (float)base[2 * Cc + lane]);
        m = mn;
    }

    __shared__ float sm[16], sl[16], sO[16][64];
    if (lane == 0) { sm[wv] = m; sl[wv] = l; }
    sO[wv][lane] = Od;
    __syncthreads();

    if (tid < 64) {
        float M2 = sm[0];
#pragma unroll
        for (int i = 1; i < 16; ++i) M2 = fmaxf(M2, sm[i]);
        float L = 0.f, OO = 0.f;
#pragma unroll
        for (int i = 0; i < 16; ++i) {
            float f = __expf(sm[i] - M2);
            L += sl[i] * f;
            OO += sO[i][tid] * f;
        }
        float* pp = P + (size_t)((b * NHh + nh) * 4 + sidx) * 66;
        if (tid == 0) { pp[0] = M2; pp[1] = L; }
        pp[2 + tid] = OO;
    }
}

__global__ __launch_bounds__(64) void cls_merge(
    const float* __restrict__ P, _Float16* __restrict__ attH)
{
    const int nh = blockIdx.x, b = blockIdx.y;
    const int tid = threadIdx.x;
    const float* p0 = P + (size_t)(b * NHh + nh) * 4 * 66;
    float M2 = fmaxf(fmaxf(p0[0], p0[66]), fmaxf(p0[132], p0[198]));
    float L = 0.f, OO = 0.f;
#pragma unroll
    for (int i = 0; i < 4; ++i) {
        const float* pp = p0 + i * 66;
        float f = __expf(pp[0] - M2);
        L += pp[1] * f;
        OO += pp[2 + tid] * f;
    }
    attH[(size_t)(b * Nt) * Cc + nh * HDd + tid] = (_Float16)(OO / L);
}

// ---------------------------------------------------------------------------
extern "C" void kernel_launch(void* const* d_in, const int* in_sizes, int n_in,
                              void* d_out, int out_size, void* d_ws, size_t ws_size,
                              hipStream_t stream)
{
    const float* x     = (const float*)d_in[0];
    const float* Wqkv  = (const float*)d_in[1];
    const float* Wproj = (const float*)d_in[2];
    const float* bproj = (const float*)d_in[3];
    float* out = (float*)d_out;

    _Float16* qkvh;   hipGetSymbolAddress((void**)&qkvh,   HIP_SYMBOL(g_qkvh));
    float*    Ocol;   hipGetSymbolAddress((void**)&Ocol,   HIP_SYMBOL(g_Ocol));
    float*    mcol;   hipGetSymbolAddress((void**)&mcol,   HIP_SYMBOL(g_mcol));
    float*    lcol;   hipGetSymbolAddress((void**)&lcol,   HIP_SYMBOL(g_lcol));
    _Float16* xh;     hipGetSymbolAddress((void**)&xh,     HIP_SYMBOL(g_xh));
    _Float16* attH;   hipGetSymbolAddress((void**)&attH,   HIP_SYMBOL(g_attH));
    _Float16* WqkvT;  hipGetSymbolAddress((void**)&WqkvT,  HIP_SYMBOL(g_WqkvT));
    _Float16* WprojT; hipGetSymbolAddress((void**)&WprojT, HIP_SYMBOL(g_WprojT));
    float*    clsP;   hipGetSymbolAddress((void**)&clsP,   HIP_SYMBOL(g_clsP));

    // 0) prep
    cvt_f16<<<4096, 256, 0, stream>>>(x, xh, (Mrows * Cc) / 4);
    transpose_f16<<<dim3(C3 / 32, Cc / 32), 256, 0, stream>>>(Wqkv, WqkvT, Cc, C3);
    transpose_f16<<<dim3(Cc / 32, Cc / 32), 256, 0, stream>>>(Wproj, WprojT, Cc, Cc);

    // 1) qkv = x @ W_qkv  (fp16 out), 256x256 tiles
    gemm_f16<_Float16, 256><<<dim3(C3 / 256, Mpad / 256), 512, 0, stream>>>(
        xh, WqkvT, nullptr, qkvh, Mrows, C3, Cc);

    // 2) attention (MFMA)
    cc_attn<0><<<dim3(Ws, NHh, B_), 64, 0, stream>>>(qkvh, Ocol, mcol, lcol, attH);
    cls_part<<<dim3(NHh, B_, 4), 1024, 0, stream>>>(qkvh, clsP);
    cls_merge<<<dim3(NHh, B_), 64, 0, stream>>>(clsP, attH);
    cc_attn<1><<<dim3(Hs, NHh, B_), 64, 0, stream>>>(qkvh, Ocol, mcol, lcol, attH);

    // 3) out = attH @ W_proj + b_proj  (fp32 out), 128x256 tiles
    gemm_f16<float, 128><<<dim3(Cc / 256, Mpad / 128), 512, 0, stream>>>(
        attH, WprojT, bproj, out, Mrows, Cc, Cc);
}

// Round 9
// 495.015 us; speedup vs baseline: 1.0182x; 1.0182x over previous
//
#include <hip/hip_runtime.h>
#include <math.h>

#define B_   8
#define Hs   56
#define Ws   56
#define Cc   768
#define NHh  12
#define HDd  64
#define Nt   3137
#define HW_  3136
#define C3   2304
#define SCALE 0.125f
#define Mrows (B_ * Nt)        // 25096
#define Mpad  (99 * 256)       // 25344 (multiple of 256 and 128)

typedef _Float16 half8  __attribute__((ext_vector_type(8)));
typedef _Float16 half4  __attribute__((ext_vector_type(4)));
typedef _Float16 half2_ __attribute__((ext_vector_type(2)));
typedef float floatx4 __attribute__((ext_vector_type(4)));

#define WAITV(N) asm volatile("s_waitcnt vmcnt(" #N ")" ::: "memory")
#define WAITL    asm volatile("s_waitcnt lgkmcnt(0)" ::: "memory")

__device__ __forceinline__ void barrier_mem() {
    asm volatile("" ::: "memory");
    __builtin_amdgcn_s_barrier();
    asm volatile("" ::: "memory");
}

__device__ __forceinline__ void gload_lds16(const _Float16* g, _Float16* l) {
    __builtin_amdgcn_global_load_lds(
        (const __attribute__((address_space(1))) void*)g,
        (__attribute__((address_space(3))) void*)l, 16, 0, 0);
}

// ---------------- scratch (__device__ globals) -----------------------------
__device__ _Float16 g_qkvh[(size_t)Mrows * C3];          // fp16 qkv (115 MB)
__device__ float    g_Ocol[(size_t)B_ * NHh * HW_ * HDd];
__device__ float    g_mcol[(size_t)B_ * NHh * HW_];
__device__ float    g_lcol[(size_t)B_ * NHh * HW_];
__device__ _Float16 g_xh[(size_t)Mpad * Cc];
__device__ _Float16 g_attH[(size_t)Mpad * Cc];
__device__ _Float16 g_WqkvT[(size_t)C3 * Cc];
__device__ _Float16 g_WprojT[(size_t)Cc * Cc];
__device__ float    g_clsP[(size_t)B_ * NHh * 4 * 66];   // per-partial: m,l,O[64]

// ---------------- fp32 -> fp16 convert -------------------------------------
__global__ __launch_bounds__(256) void cvt_f16(
    const float* __restrict__ in, _Float16* __restrict__ out, int n4)
{
    for (int i = blockIdx.x * 256 + threadIdx.x; i < n4; i += gridDim.x * 256) {
        float4 v = ((const float4*)in)[i];
        half4 h = { (_Float16)v.x, (_Float16)v.y, (_Float16)v.z, (_Float16)v.w };
        ((half4*)out)[i] = h;
    }
}

// ---------------- fp32 [R][Cq] -> fp16 transposed [Cq][R] ------------------
__global__ __launch_bounds__(256) void transpose_f16(
    const float* __restrict__ in, _Float16* __restrict__ out, int R, int Cq)
{
    __shared__ float t[32][33];
    const int c0 = blockIdx.x * 32, r0 = blockIdx.y * 32;
    const int tx = threadIdx.x & 31, ty = threadIdx.x >> 5;
#pragma unroll
    for (int i = 0; i < 32; i += 8)
        t[ty + i][tx] = in[(size_t)(r0 + ty + i) * Cq + c0 + tx];
    __syncthreads();
#pragma unroll
    for (int i = 0; i < 32; i += 8)
        out[(size_t)(c0 + ty + i) * R + r0 + tx] = (_Float16)t[tx][ty + i];
}

// ---------------------------------------------------------------------------
// fp16 MFMA GEMM (R7 loop, verified 129.5us on gemm1): 256x256 tile, BK=32,
// 512 thr (8 waves 2Mx4N). FOUR rotating LDS buffers, staging depth-3 with
// counted vmcnt (never 0 in steady state). One barrier per K-tile; register
// ping-pong fragments so MFMAs have no lgkm dependency.
// ---------------------------------------------------------------------------
template <typename OutT, int BM>
__global__ __launch_bounds__(512, 2) void gemm_f16(
    const _Float16* __restrict__ A, const _Float16* __restrict__ Bt,
    const float* __restrict__ bias, OutT* __restrict__ Cm,
    int M, int Nd, int K)
{
    constexpr int MI   = BM / 32;        // 16-row groups per wave (8 or 4)
    constexpr int LA   = BM / 128;       // A loads/thread per K-tile (2 or 1)
    constexpr int ASZh = BM * 32;        // halfs per A K-tile buffer
    constexpr int BSZh = 256 * 32;       // halfs per B K-tile buffer
    constexpr int BUFh = ASZh + BSZh;
    constexpr size_t MAINB = (size_t)4 * BUFh * 2;
    constexpr size_t EPIB  = sizeof(OutT) == 2 ? (size_t)BM * 280 * 2
                                               : (size_t)BM * 140 * 4;
    constexpr size_t SMEMB = MAINB > EPIB ? MAINB : EPIB;
    __shared__ __align__(16) char smem[SMEMB];

    const int tid = threadIdx.x;
    const int wave = tid >> 6, lane = tid & 63;
    const int wm = wave & 1, wn = wave >> 1;

    // panel swizzle: 16 row-blocks per panel, col-major within panel
    const int bid = blockIdx.y * gridDim.x + blockIdx.x;
    const int perPanel = gridDim.x * 16;
    const int panel = bid / perPanel;
    const int rowsIn = min(16, (int)gridDim.y - panel * 16);
    const int rem = bid - panel * perPanel;
    const int by = panel * 16 + rem % rowsIn;
    const int bx = rem / rowsIn;
    const int mBase = by * BM, nBase = bx * 256;

    // staging geometry (verified): unit u (16B) -> row ((u>>6)<<4)+(u&15),
    // kc=(u>>4)&3, LDS byte off u*16. Thread handles u = i*512 + tid.
    const int mU  = ((tid >> 6) << 4) + (tid & 15);
    const int kcU = (tid >> 4) & 3;
    const _Float16* ga = A  + (size_t)(mBase + mU) * K + kcU * 8;
    const _Float16* gb = Bt + (size_t)(nBase + mU) * K + kcU * 8;

    auto stage = [&](int t) {
        char* base = smem + (size_t)(t & 3) * (BUFh * 2);
        _Float16* lA = (_Float16*)base + wave * 512;
        _Float16* lB = (_Float16*)base + ASZh + wave * 512;
        const _Float16* gaK = ga + t * 32;
        const _Float16* gbK = gb + t * 32;
#pragma unroll
        for (int i = 0; i < LA; ++i)
            gload_lds16(gaK + (size_t)i * 128 * K, lA + i * 4096);
#pragma unroll
        for (int i = 0; i < 2; ++i)
            gload_lds16(gbK + (size_t)i * 128 * K, lB + i * 4096);
    };

    // fragment read: group g (16 rows x 32 k = 512 halfs); conflict-free b128
    const int fo = (lane >> 4) * 128 + (lane & 15) * 8;
    auto readFrags = [&](int t, half8 (&a)[MI], half8 (&b)[4]) {
        const _Float16* bufA = (const _Float16*)(smem + (size_t)(t & 3) * (BUFh * 2));
        const _Float16* bufB = bufA + ASZh;
#pragma unroll
        for (int mi = 0; mi < MI; ++mi)
            a[mi] = *(const half8*)&bufA[(wm * MI + mi) * 512 + fo];
#pragma unroll
        for (int ni = 0; ni < 4; ++ni)
            b[ni] = *(const half8*)&bufB[(wn * 4 + ni) * 512 + fo];
    };

    floatx4 acc[MI][4] = {};
    half8 aX[MI], bX[4], aY[MI], bY[4];

    const int NT = K >> 5;               // 24 K-tiles of 32 (even)
    stage(0); stage(1); stage(2);        // depth-3 prologue
    if constexpr (LA == 2) { WAITV(8); } else { WAITV(6); }   // tile 0 resident
    barrier_mem();
    readFrags(0, aX, bX);

    auto tileBody = [&](int t, half8 (&aC)[MI], half8 (&bC)[4],
                        half8 (&aN)[MI], half8 (&bN)[4]) {
        if (t <= NT - 3) {
            if constexpr (LA == 2) { WAITV(4); } else { WAITV(3); }
        } else {
            WAITV(0);
        }
        barrier_mem();                    // t and t+1 resident for ALL waves
        if (t + 3 < NT) stage(t + 3);     // into buf(t-1): free since t-2
        __builtin_amdgcn_s_setprio(1);
        if (t + 1 < NT) readFrags(t + 1, aN, bN);   // drains behind MFMAs
#pragma unroll
        for (int mi = 0; mi < MI; ++mi)
#pragma unroll
            for (int ni = 0; ni < 4; ++ni)
                acc[mi][ni] = __builtin_amdgcn_mfma_f32_16x16x32_f16(
                    bC[ni], aC[mi], acc[mi][ni], 0, 0, 0);
        __builtin_amdgcn_s_setprio(0);
    };

    for (int t = 0; t < NT; t += 2) {
        tileBody(t,     aX, bX, aY, bY);
        tileBody(t + 1, aY, bY, aX, bX);
    }
    WAITL;
    barrier_mem();                        // LDS free for epilogue reuse

    // -------- epilogue: LDS bounce --------
    const int mlBase = wm * (BM / 2) + (lane & 15);
    const int nlBase = wn * 64 + ((lane >> 4) << 2);

    if constexpr (sizeof(OutT) == 2) {
        _Float16* Ch = (_Float16*)smem;          // [BM][280]
#pragma unroll
        for (int ni = 0; ni < 4; ++ni) {
            const int nl = nlBase + ni * 16;
#pragma unroll
            for (int mi = 0; mi < MI; ++mi) {
                const int ml = mlBase + mi * 16;
                floatx4 v = acc[mi][ni];
                half4 h = { (_Float16)v[0], (_Float16)v[1],
                            (_Float16)v[2], (_Float16)v[3] };
                *(half4*)&Ch[ml * 280 + nl] = h;
            }
        }
        barrier_mem();
#pragma unroll
        for (int i = 0; i < BM / 16; ++i) {
            const int f = i * 512 + tid;
            const int row = f >> 5, u = f & 31;
            const int gm = mBase + row;
            if (gm < M)
                *(half8*)&Cm[(size_t)gm * Nd + nBase + u * 8] =
                    *(const half8*)&Ch[row * 280 + u * 8];
        }
    } else {
        float* Cf = (float*)smem;                // [BM][140]
#pragma unroll
        for (int nh = 0; nh < 2; ++nh) {
            barrier_mem();
            if ((wn >> 1) == nh) {
#pragma unroll
                for (int ni = 0; ni < 4; ++ni) {
                    const int n0 = nBase + wn * 64 + ((lane >> 4) << 2) + ni * 16;
                    float4 bv = bias ? *(const float4*)&bias[n0]
                                     : make_float4(0.f, 0.f, 0.f, 0.f);
                    const int nl = (wn & 1) * 64 + ((lane >> 4) << 2) + ni * 16;
#pragma unroll
                    for (int mi = 0; mi < MI; ++mi) {
                        const int ml = mlBase + mi * 16;
                        floatx4 v = acc[mi][ni];
                        float4 o = make_float4(v[0] + bv.x, v[1] + bv.y,
                                               v[2] + bv.z, v[3] + bv.w);
                        *(float4*)&Cf[ml * 140 + nl] = o;
                    }
                }
            }
            barrier_mem();
#pragma unroll
            for (int i = 0; i < BM / 16; ++i) {
                const int f = i * 512 + tid;
                const int row = f >> 5, u = f & 31;
                const int gm = mBase + row;
                if (gm < M)
                    *(float4*)&Cm[(size_t)gm * Nd + nBase + nh * 128 + u * 4] =
                        *(const float4*)&Cf[row * 140 + u * 4];
            }
        }
    }
}

// ---------------------------------------------------------------------------
// R9: projection GEMM (fp32 out) at 128x128 / 256 thr / 64 KiB LDS ->
// 2 blocks/CU. Same R7 loop (4 rotating buffers, depth-3, counted vmcnt,
// reg ping-pong); the co-resident block covers gate/barrier stalls (m114
// implicit overlap), which the 1-block/CU 256-tile cannot. 4 waves 2Mx2N,
// per-wave 64x64 (acc[4][4]); loads/thread/tile = 4 (same gate counts).
// Epilogue: [128][68] fp32 LDS bounce, two 64-col passes, coalesced stores.
// ---------------------------------------------------------------------------
__global__ __launch_bounds__(256, 2) void gemm_g2(
    const _Float16* __restrict__ A, const _Float16* __restrict__ Bt,
    const float* __restrict__ bias, float* __restrict__ Cm,
    int M, int Nd, int K)
{
    constexpr int ASZh = 128 * 32;       // halfs per A K-tile buffer
    constexpr int BUFh = 2 * ASZh;       // A + B
    __shared__ __align__(16) char smem[(size_t)4 * BUFh * 2];   // 64 KiB

    const int tid = threadIdx.x;
    const int wave = tid >> 6, lane = tid & 63;
    const int wm = wave & 1, wn = wave >> 1;          // 2M x 2N

    // panel swizzle
    const int bid = blockIdx.y * gridDim.x + blockIdx.x;
    const int perPanel = gridDim.x * 16;
    const int panel = bid / perPanel;
    const int rowsIn = min(16, (int)gridDim.y - panel * 16);
    const int rem = bid - panel * perPanel;
    const int by = panel * 16 + rem % rowsIn;
    const int bx = rem / rowsIn;
    const int mBase = by * 128, nBase = bx * 128;

    // staging: A/B each 512 units; thread handles u = i*256 + tid, i in {0,1}
    const int mU  = ((tid >> 6) << 4) + (tid & 15);
    const int kcU = (tid >> 4) & 3;
    const _Float16* ga = A  + (size_t)(mBase + mU) * K + kcU * 8;
    const _Float16* gb = Bt + (size_t)(nBase + mU) * K + kcU * 8;

    auto stage = [&](int t) {
        char* base = smem + (size_t)(t & 3) * (BUFh * 2);
        _Float16* lA = (_Float16*)base + wave * 512;
        _Float16* lB = (_Float16*)base + ASZh + wave * 512;
        const _Float16* gaK = ga + t * 32;
        const _Float16* gbK = gb + t * 32;
#pragma unroll
        for (int i = 0; i < 2; ++i)
            gload_lds16(gaK + (size_t)i * 64 * K, lA + i * 2048);
#pragma unroll
        for (int i = 0; i < 2; ++i)
            gload_lds16(gbK + (size_t)i * 64 * K, lB + i * 2048);
    };

    const int fo = (lane >> 4) * 128 + (lane & 15) * 8;
    auto readFrags = [&](int t, half8 (&a)[4], half8 (&b)[4]) {
        const _Float16* bufA = (const _Float16*)(smem + (size_t)(t & 3) * (BUFh * 2));
        const _Float16* bufB = bufA + ASZh;
#pragma unroll
        for (int mi = 0; mi < 4; ++mi)
            a[mi] = *(const half8*)&bufA[(wm * 4 + mi) * 512 + fo];
#pragma unroll
        for (int ni = 0; ni < 4; ++ni)
            b[ni] = *(const half8*)&bufB[(wn * 4 + ni) * 512 + fo];
    };

    floatx4 acc[4][4] = {};
    half8 aX[4], bX[4], aY[4], bY[4];

    const int NT = K >> 5;               // 24 (even)
    stage(0); stage(1); stage(2);
    WAITV(8);                            // tile 0 resident (t+1,t+2 in flight)
    barrier_mem();
    readFrags(0, aX, bX);

    auto tileBody = [&](int t, half8 (&aC)[4], half8 (&bC)[4],
                        half8 (&aN)[4], half8 (&bN)[4]) {
        if (t <= NT - 3)      { WAITV(4); }
        else                  { WAITV(0); }
        barrier_mem();
        if (t + 3 < NT) stage(t + 3);
        __builtin_amdgcn_s_setprio(1);
        if (t + 1 < NT) readFrags(t + 1, aN, bN);
#pragma unroll
        for (int mi = 0; mi < 4; ++mi)
#pragma unroll
            for (int ni = 0; ni < 4; ++ni)
                acc[mi][ni] = __builtin_amdgcn_mfma_f32_16x16x32_f16(
                    bC[ni], aC[mi], acc[mi][ni], 0, 0, 0);
        __builtin_amdgcn_s_setprio(0);
    };

    for (int t = 0; t < NT; t += 2) {
        tileBody(t,     aX, bX, aY, bY);
        tileBody(t + 1, aY, bY, aX, bX);
    }
    WAITL;
    barrier_mem();

    // -------- epilogue: [128][68] fp32 bounce, two 64-col passes --------
    float* Cf = (float*)smem;
    const int mlBase = wm * 64 + (lane & 15);
#pragma unroll
    for (int p = 0; p < 2; ++p) {
        barrier_mem();
        if (wn == p) {
#pragma unroll
            for (int ni = 0; ni < 4; ++ni) {
                const int nq = ni * 16 + ((lane >> 4) << 2);
                const int n0 = nBase + p * 64 + nq;
                float4 bv = *(const float4*)&bias[n0];
#pragma unroll
                for (int mi = 0; mi < 4; ++mi) {
                    const int ml = mlBase + mi * 16;
                    floatx4 v = acc[mi][ni];
                    float4 o = make_float4(v[0] + bv.x, v[1] + bv.y,
                                           v[2] + bv.z, v[3] + bv.w);
                    *(float4*)&Cf[ml * 68 + nq] = o;
                }
            }
        }
        barrier_mem();
#pragma unroll
        for (int i = 0; i < 8; ++i) {
            const int f = i * 256 + tid;
            const int row = f >> 4, u = f & 15;
            const int gm = mBase + row;
            if (gm < M)
                *(float4*)&Cm[(size_t)gm * Nd + nBase + p * 64 + u * 4] =
                    *(const float4*)&Cf[row * 68 + u * 4];
        }
    }
}

// ---------------------------------------------------------------------------
// R6 MFMA criss-cross attention (unchanged). One wave per (x, nh, b).
// ---------------------------------------------------------------------------
template <int MODE>
__global__ __launch_bounds__(64) void cc_attn(
    const _Float16* __restrict__ qkvh,
    float* __restrict__ Ocol, float* __restrict__ mcol,
    float* __restrict__ lcol, _Float16* __restrict__ attH)
{
    constexpr int NK = (MODE == 0) ? 57 : 56;
    const int x = blockIdx.x, nh = blockIdx.y, b = blockIdx.z;
    const int lane = threadIdx.x;
    const int q15 = lane & 15, g = lane >> 4;

    __shared__ __align__(16) char smem[18944];
    _Float16* Vt = (_Float16*)smem;                 // [64][72], rotated rows
    _Float16* Pl = (_Float16*)(smem + 9216);        // [64][72]
    float*    ML = (float*)(smem + 18432);          // [64] m, [64] l
    float*    Ol = (float*)smem;                    // [64][68] overlay

    const _Float16* base_b = qkvh + (size_t)(b * Nt) * C3 + nh * HDd;

    auto nrow_k = [&](int key) -> int {
        key = min(key, NK - 1);
        if (MODE == 0) return (key == 0) ? 0 : ((key - 1) * Ws + x + 1);
        return x * Ws + key + 1;
    };
    auto nrow_q = [&](int q) -> int {
        q = min(q, 55);
        return (MODE == 0) ? (q * Ws + x + 1) : (x * Ws + q + 1);
    };

    // ---- K/Q fragments from global (per-lane rows) ----
    half8 Kf[4][2], Qf[4][2];
#pragma unroll
    for (int t = 0; t < 4; ++t) {
        const _Float16* kp = base_b + (size_t)nrow_k(t * 16 + q15) * C3 + Cc;
        const _Float16* qp = base_b + (size_t)nrow_q(t * 16 + q15) * C3;
#pragma unroll
        for (int kk = 0; kk < 2; ++kk) {
            Kf[t][kk] = *(const half8*)(kp + kk * 32 + g * 8);
            Qf[t][kk] = *(const half8*)(qp + kk * 32 + g * 8);
        }
    }

    // ---- stage V^T into LDS (rotated, zero-padded keys >= NK) ----
#pragma unroll
    for (int it = 0; it < 8; ++it) {
        const int i = it * 64 + lane;
        const int j = i >> 3, c = i & 7;
        half8 v = {};
        if (j < NK)
            v = *(const half8*)(base_b + (size_t)nrow_k(j) * C3 + 2 * Cc + c * 8);
#pragma unroll
        for (int e = 0; e < 8; ++e)
            Vt[(c * 8 + e) * 72 + ((j + 8 * c) & 63)] = v[e];
    }

    // ---- S^T = K * Q^T ----
    floatx4 S[4][4] = {};   // [kt][qt]
#pragma unroll
    for (int kt = 0; kt < 4; ++kt)
#pragma unroll
        for (int qt = 0; qt < 4; ++qt)
#pragma unroll
            for (int kk = 0; kk < 2; ++kk)
                S[kt][qt] = __builtin_amdgcn_mfma_f32_16x16x32_f16(
                    Kf[kt][kk], Qf[qt][kk], S[kt][qt], 0, 0, 0);

    // ---- softmax per query column (in-lane 16 + cross-g shfl) ----
    float mq[4], lq[4];
#pragma unroll
    for (int qt = 0; qt < 4; ++qt) {
        const int q = qt * 16 + q15;
        float sv[4][4];
        float mm = -1e30f;
#pragma unroll
        for (int kt = 0; kt < 4; ++kt)
#pragma unroll
            for (int r = 0; r < 4; ++r) {
                const int key = kt * 16 + g * 4 + r;
                float s = S[kt][qt][r] * SCALE;
                const bool bad = (key >= NK) || (MODE == 1 && key == q);
                sv[kt][r] = bad ? -1e30f : s;
                mm = fmaxf(mm, sv[kt][r]);
            }
        mm = fmaxf(mm, __shfl_xor(mm, 16, 64));
        mm = fmaxf(mm, __shfl_xor(mm, 32, 64));
        float ll = 0.f;
#pragma unroll
        for (int kt = 0; kt < 4; ++kt) {
            half4 ph;
#pragma unroll
            for (int r = 0; r < 4; ++r) {
                const float p = __expf(sv[kt][r] - mm);
                ll += p;
                ph[r] = (_Float16)p;
            }
            *(half4*)&Pl[q * 72 + kt * 16 + g * 4] = ph;
        }
        ll += __shfl_xor(ll, 16, 64);
        ll += __shfl_xor(ll, 32, 64);
        mq[qt] = mm; lq[qt] = ll;
    }

    if (g == 0) {
        if (MODE == 0) {
#pragma unroll
            for (int qt = 0; qt < 4; ++qt) {
                const int q = qt * 16 + q15;
                if (q < 56) {
                    const size_t qi = (size_t)((b * NHh + nh) * HW_) + q * Ws + x;
                    mcol[qi] = mq[qt]; lcol[qi] = lq[qt];
                }
            }
        } else {
#pragma unroll
            for (int qt = 0; qt < 4; ++qt) {
                ML[qt * 16 + q15] = mq[qt];
                ML[64 + qt * 16 + q15] = lq[qt];
            }
        }
    }
    __syncthreads();

    // ---- O^T = V^T * P^T ----
    half8 Pf[4][2];
#pragma unroll
    for (int qt = 0; qt < 4; ++qt)
#pragma unroll
        for (int kk = 0; kk < 2; ++kk)
            Pf[qt][kk] = *(const half8*)&Pl[(qt * 16 + q15) * 72 + kk * 32 + g * 8];

    floatx4 O[4][4] = {};   // [dt][qt]
#pragma unroll
    for (int dt = 0; dt < 4; ++dt) {
        const int d = dt * 16 + q15;
        const int rot = 8 * (d >> 3);
        half8 Vf0 = *(const half8*)&Vt[d * 72 + ((0 + g * 8 + rot) & 63)];
        half8 Vf1 = *(const half8*)&Vt[d * 72 + ((32 + g * 8 + rot) & 63)];
#pragma unroll
        for (int qt = 0; qt < 4; ++qt) {
            O[dt][qt] = __builtin_amdgcn_mfma_f32_16x16x32_f16(
                Vf0, Pf[qt][0], O[dt][qt], 0, 0, 0);
            O[dt][qt] = __builtin_amdgcn_mfma_f32_16x16x32_f16(
                Vf1, Pf[qt][1], O[dt][qt], 0, 0, 0);
        }
    }
    __syncthreads();   // all Vt/Pl reads done before Ol overlay writes

    // ---- bounce O^T -> row-major rows in LDS ----
#pragma unroll
    for (int dt = 0; dt < 4; ++dt)
#pragma unroll
        for (int qt = 0; qt < 4; ++qt) {
            float4 f = { O[dt][qt][0], O[dt][qt][1], O[dt][qt][2], O[dt][qt][3] };
            *(float4*)&Ol[(qt * 16 + q15) * 68 + dt * 16 + g * 4] = f;
        }
    __syncthreads();

    // ---- per-lane row output ----
    const int qq = lane;
    if (qq < 56) {
        if (MODE == 0) {
            const size_t qi = (size_t)((b * NHh + nh) * HW_) + qq * Ws + x;
            float* op = Ocol + qi * HDd;
#pragma unroll
            for (int i = 0; i < 16; ++i)
                *(float4*)(op + i * 4) = *(const float4*)&Ol[qq * 68 + i * 4];
        } else {
            const size_t qi = (size_t)((b * NHh + nh) * HW_) + x * Ws + qq;
            const float mc = mcol[qi], lc = lcol[qi];
            const float mr = ML[qq], lr = ML[64 + qq];
            const float mn = fmaxf(mc, mr);
            const float fc = __expf(mc - mn);
            const float fr = __expf(mr - mn);
            const float inv = 1.f / (lc * fc + lr * fr);
            const int n = x * Ws + qq + 1;
            _Float16* op = attH + (size_t)(b * Nt + n) * Cc + nh * HDd;
            const float* ocp = Ocol + qi * HDd;
#pragma unroll
            for (int i = 0; i < 16; ++i) {
                float4 oc = *(const float4*)(ocp + i * 4);
                const float* oo = &Ol[qq * 68 + i * 4];
                half4 r = { (_Float16)((oc.x * fc + oo[0] * fr) * inv),
                            (_Float16)((oc.y * fc + oo[1] * fr) * inv),
                            (_Float16)((oc.z * fc + oo[2] * fr) * inv),
                            (_Float16)((oc.w * fc + oo[3] * fr) * inv) };
                *(half4*)(op + i * 4) = r;
            }
        }
    }
}

// ---------------------------------------------------------------------------
// Cls-token attention, 4-way key-split; merged by cls_merge.
// ---------------------------------------------------------------------------
__global__ __launch_bounds__(1024) void cls_part(
    const _Float16* __restrict__ qkvh, float* __restrict__ P)
{
    const int nh = blockIdx.x, b = blockIdx.y, sidx = blockIdx.z;
    const int j0 = sidx * 785, j1 = min(Nt, j0 + 785);
    const int tid = threadIdx.x;
    const int lane = tid & 63, wv = tid >> 6;

    const float qd = (float)qkvh[(size_t)(b * Nt) * C3 + nh * HDd + lane];
    float m = -INFINITY, l = 0.f, Od = 0.f;

    for (int j = j0 + wv; j < j1; j += 16) {
        const _Float16* base = qkvh + (size_t)(b * Nt + j) * C3 + nh * HDd;
        float prod = qd * (float)base[Cc + lane];
#pragma unroll
        for (int off = 32; off >= 1; off >>= 1)
            prod += __shfl_xor(prod, off, 64);
        float s = prod * SCALE;
        float mn = fmaxf(m, s);
        float corr = __expf(m - mn);
        float p = __expf(s - mn);
        l = l * corr + p;
        Od = fmaf(Od, corr, p * (float)base[2 * Cc + lane]);
        m = mn;
    }

    __shared__ float sm[16], sl[16], sO[16][64];
    if (lane == 0) { sm[wv] = m; sl[wv] = l; }
    sO[wv][lane] = Od;
    __syncthreads();

    if (tid < 64) {
        float M2 = sm[0];
#pragma unroll
        for (int i = 1; i < 16; ++i) M2 = fmaxf(M2, sm[i]);
        float L = 0.f, OO = 0.f;
#pragma unroll
        for (int i = 0; i < 16; ++i) {
            float f = __expf(sm[i] - M2);
            L += sl[i] * f;
            OO += sO[i][tid] * f;
        }
        float* pp = P + (size_t)((b * NHh + nh) * 4 + sidx) * 66;
        if (tid == 0) { pp[0] = M2; pp[1] = L; }
        pp[2 + tid] = OO;
    }
}

__global__ __launch_bounds__(64) void cls_merge(
    const float* __restrict__ P, _Float16* __restrict__ attH)
{
    const int nh = blockIdx.x, b = blockIdx.y;
    const int tid = threadIdx.x;
    const float* p0 = P + (size_t)(b * NHh + nh) * 4 * 66;
    float M2 = fmaxf(fmaxf(p0[0], p0[66]), fmaxf(p0[132], p0[198]));
    float L = 0.f, OO = 0.f;
#pragma unroll
    for (int i = 0; i < 4; ++i) {
        const float* pp = p0 + i * 66;
        float f = __expf(pp[0] - M2);
        L += pp[1] * f;
        OO += pp[2 + tid] * f;
    }
    attH[(size_t)(b * Nt) * Cc + nh * HDd + tid] = (_Float16)(OO / L);
}

// ---------------------------------------------------------------------------
extern "C" void kernel_launch(void* const* d_in, const int* in_sizes, int n_in,
                              void* d_out, int out_size, void* d_ws, size_t ws_size,
                              hipStream_t stream)
{
    const float* x     = (const float*)d_in[0];
    const float* Wqkv  = (const float*)d_in[1];
    const float* Wproj = (const float*)d_in[2];
    const float* bproj = (const float*)d_in[3];
    float* out = (float*)d_out;

    _Float16* qkvh;   hipGetSymbolAddress((void**)&qkvh,   HIP_SYMBOL(g_qkvh));
    float*    Ocol;   hipGetSymbolAddress((void**)&Ocol,   HIP_SYMBOL(g_Ocol));
    float*    mcol;   hipGetSymbolAddress((void**)&mcol,   HIP_SYMBOL(g_mcol));
    float*    lcol;   hipGetSymbolAddress((void**)&lcol,   HIP_SYMBOL(g_lcol));
    _Float16* xh;     hipGetSymbolAddress((void**)&xh,     HIP_SYMBOL(g_xh));
    _Float16* attH;   hipGetSymbolAddress((void**)&attH,   HIP_SYMBOL(g_attH));
    _Float16* WqkvT;  hipGetSymbolAddress((void**)&WqkvT,  HIP_SYMBOL(g_WqkvT));
    _Float16* WprojT; hipGetSymbolAddress((void**)&WprojT, HIP_SYMBOL(g_WprojT));
    float*    clsP;   hipGetSymbolAddress((void**)&clsP,   HIP_SYMBOL(g_clsP));

    // 0) prep
    cvt_f16<<<4096, 256, 0, stream>>>(x, xh, (Mrows * Cc) / 4);
    transpose_f16<<<dim3(C3 / 32, Cc / 32), 256, 0, stream>>>(Wqkv, WqkvT, Cc, C3);
    transpose_f16<<<dim3(Cc / 32, Cc / 32), 256, 0, stream>>>(Wproj, WprojT, Cc, Cc);

    // 1) qkv = x @ W_qkv  (fp16 out), 256x256 tiles (R7 loop, verified)
    gemm_f16<_Float16, 256><<<dim3(C3 / 256, Mpad / 256), 512, 0, stream>>>(
        xh, WqkvT, nullptr, qkvh, Mrows, C3, Cc);

    // 2) attention (MFMA)
    cc_attn<0><<<dim3(Ws, NHh, B_), 64, 0, stream>>>(qkvh, Ocol, mcol, lcol, attH);
    cls_part<<<dim3(NHh, B_, 4), 1024, 0, stream>>>(qkvh, clsP);
    cls_merge<<<dim3(NHh, B_), 64, 0, stream>>>(clsP, attH);
    cc_attn<1><<<dim3(Hs, NHh, B_), 64, 0, stream>>>(qkvh, Ocol, mcol, lcol, attH);

    // 3) out = attH @ W_proj + b_proj  (fp32 out), 128x128 / 2 blocks-per-CU
    gemm_g2<<<dim3(Cc / 128, Mpad / 128), 256, 0, stream>>>(
        attH, WprojT, bproj, out, Mrows, Cc, Cc);
}